// Round 4
// baseline (171.084 us; speedup 1.0000x reference)
//
#include <hip/hip_runtime.h>

// DigitCaps on MI355X, fp32 I/O. R15 = R14 fused kernel, UNCAPPED registers.
// R14 post-mortem: fusion correct (passed, same absmax) but __launch_bounds__
// (256,4) + final-phase code made the allocator clamp to VGPR=64 ->
// catastrophic spill (WRITE_SIZE 3.2MB, votes 119us). Matches R5/R7/R8:
// ANY occupancy hint risks spill; uncapped ~216-reg config is the only
// proven-safe one (R9). This round: identical body, plain launch_bounds(256).
// Session evidence:
//   R2: fp32 atomicAdd = CAS loop -> native int atomics only.
//   R3: seg sums winner-biased -> int64 finals.
//   R5/R7/R8/R14: VGPR cap below natural demand -> scratch spill
//     (WRITE_SIZE is the spill detector; R14: 3.2MB, VGPR=64).
//   R9: register W-slice + dc, replicated LDS atomics -> 99.4us baseline.
//   R10 neutral, R11 regression, R13 (dc->SGPR + (256,4)) neutral.
//   R14: fused one-kernel + device-atomic flush + ticket finalize -- design
//     passed; regression was purely the register cap.
//
// Sizes: B=128, J=4608, INPUT_D=8, D=8, M=4 -> N=18432 votes, C=10.
// Output = concat(output[128,10], digit_caps_new[10,8]).
// Math: output[b,c] = <(1/N) sum_n u[b,n], dc_new[c]> -> only s[b,:] needed.
//
// ws layout (BYTES):
//   [0,4)        done ticket counter
//   [64,832)     g_seg long long[96]  (col c*9+d; d==8 -> count)
//   [1024,5120)  g_s   int[1024]      (col b*8+d, scale 2^15)
//   memset span [0,5120).

#define J_POS 4608
#define SEGSTRIDE 97        // 97%32=1 -> replica r occupies bank r%32
#define NSEG 32
#define SSTRIDE 520
#define NSREP 8
#define NVOTES 18432.0f
#define DENOM  2359296.0f   // B*N
#define SEG_SCALE 32768.0f  // 2^15
#define INV_SEG_SCALE 3.0517578125e-5f

__global__ __launch_bounds__(256) void votes_kernel(
    const float* __restrict__ x,   // [B, J, 8]
    const float* __restrict__ w,   // [J, 8, 32]
    const float* __restrict__ dc,  // [10, 8]
    long long* __restrict__ g_seg, // [96]
    int* __restrict__ g_s,         // [1024]
    int* __restrict__ done,
    float* __restrict__ out)       // [0,1280): output  [1280,1360): dc_new
{
    __shared__ int seg_lds[NSEG * SEGSTRIDE];   // 12.4 KB
    __shared__ int s_lds[NSREP * SSTRIDE];      // 16.6 KB
    __shared__ float sf[1024];                  // final-phase scratch
    __shared__ float dcn[80];
    __shared__ int lastflag;

    const int t  = threadIdx.x;
    const int jg = blockIdx.x >> 1;
    const int h  = blockIdx.x & 1;      // batch half
    const int j0 = jg * 8;

    for (int i = t; i < NSEG * SEGSTRIDE; i += 256) seg_lds[i] = 0;
    for (int i = t; i < NSREP * SSTRIDE; i += 256) s_lds[i] = 0;

    const int jj   = t >> 5;           // 0..7 : this thread's j
    const int m    = (t >> 3) & 3;     // 0..3 : this thread's vote column
    const int brow = t & 7;            // 0..7 : batch row within iter
    const int j = j0 + jj;

    // ---- W slice (8 i x 8 d for this (j,m)) -> 64 registers, loaded once
    float4 wra[8], wrb[8];
    {
        const float* wp = w + (size_t)j * 256 + m * 8;
        #pragma unroll
        for (int i = 0; i < 8; ++i) {
            wra[i] = *(const float4*)(wp + i * 32);
            wrb[i] = *(const float4*)(wp + i * 32 + 4);
        }
    }

    // ---- all of dc, forced wave-uniform (SGPR class via readfirstlane)
    float dcs[80];
    #pragma unroll
    for (int c = 0; c < 10; ++c) {
        const float4 a = *(const float4*)(dc + c * 8);
        const float4 b = *(const float4*)(dc + c * 8 + 4);
        dcs[c*8+0] = __uint_as_float(__builtin_amdgcn_readfirstlane(__float_as_uint(a.x)));
        dcs[c*8+1] = __uint_as_float(__builtin_amdgcn_readfirstlane(__float_as_uint(a.y)));
        dcs[c*8+2] = __uint_as_float(__builtin_amdgcn_readfirstlane(__float_as_uint(a.z)));
        dcs[c*8+3] = __uint_as_float(__builtin_amdgcn_readfirstlane(__float_as_uint(a.w)));
        dcs[c*8+4] = __uint_as_float(__builtin_amdgcn_readfirstlane(__float_as_uint(b.x)));
        dcs[c*8+5] = __uint_as_float(__builtin_amdgcn_readfirstlane(__float_as_uint(b.y)));
        dcs[c*8+6] = __uint_as_float(__builtin_amdgcn_readfirstlane(__float_as_uint(b.z)));
        dcs[c*8+7] = __uint_as_float(__builtin_amdgcn_readfirstlane(__float_as_uint(b.w)));
    }

    int* const segp = &seg_lds[((t >> 1) & (NSEG - 1)) * SEGSTRIDE];
    // lanes sharing one b in a wave = {jj&1, m} -> 8 distinct replicas: 1-way
    int* const sp = &s_lds[((t >> 3) & (NSREP - 1)) * SSTRIDE];

    __syncthreads();

    // ---- software-pipelined x loads (1-ahead) to hide HBM latency
    const float* xp0 = x + ((size_t)(h * 64 + brow) * J_POS + j) * 8;
    float4 nx0 = *(const float4*)xp0;
    float4 nx1 = *(const float4*)(xp0 + 4);

    #pragma unroll 1
    for (int it = 0; it < 8; ++it) {
        const int bl = it * 8 + brow;       // local b 0..63
        const float4 x0 = nx0, x1 = nx1;
        if (it < 7) {
            const float* xp = x + ((size_t)(h * 64 + bl + 8) * J_POS + j) * 8;
            nx0 = *(const float4*)xp;
            nx1 = *(const float4*)(xp + 4);
        }
        const float xf[8] = {x0.x,x0.y,x0.z,x0.w,x1.x,x1.y,x1.z,x1.w};

        // ---- one vote: u[8], all operands in registers
        float u[8] = {0,0,0,0,0,0,0,0};
        #pragma unroll
        for (int i = 0; i < 8; ++i) {
            const float xi = xf[i];
            u[0] += xi * wra[i].x; u[1] += xi * wra[i].y;
            u[2] += xi * wra[i].z; u[3] += xi * wra[i].w;
            u[4] += xi * wrb[i].x; u[5] += xi * wrb[i].y;
            u[6] += xi * wrb[i].z; u[7] += xi * wrb[i].w;
        }

        // ---- argmax over 10 caps (strict > = first max, jnp)
        float best = -3.402823466e38f;
        int bc = 0;
        #pragma unroll
        for (int c = 0; c < 10; ++c) {
            const float sim = u[0]*dcs[c*8+0] + u[1]*dcs[c*8+1]
                            + u[2]*dcs[c*8+2] + u[3]*dcs[c*8+3]
                            + u[4]*dcs[c*8+4] + u[5]*dcs[c*8+5]
                            + u[6]*dcs[c*8+6] + u[7]*dcs[c*8+7];
            if (sim > best) { best = sim; bc = c; }
        }

        // ---- fixed-point LDS atomics, fire-and-forget
        const int o = bc * 9;
        const int sb = bl * 8;
        #pragma unroll
        for (int d = 0; d < 8; ++d) {
            const int q = __float2int_rn(u[d] * SEG_SCALE);
            atomicAdd(&segp[o + d], q);
            atomicAdd(&sp[sb + d], q);
        }
        atomicAdd(&segp[o + 8], 1);
    }

    __syncthreads();

    // ---- flush partials: device-scope integer atomics into tiny globals.
    // seg as int64 (winner-biased, int32 would overflow at full-N totals);
    // s as int32 (unbiased, 238-sigma headroom). Fire-and-forget; hardware
    // drains outstanding ops before the threadfence below.
    if (t < 90) {
        int v = 0;
        #pragma unroll
        for (int r = 0; r < NSEG; ++r) v += seg_lds[r * SEGSTRIDE + t];
        atomicAdd((unsigned long long*)&g_seg[t],
                  (unsigned long long)(long long)v);
    }
    #pragma unroll
    for (int e = t; e < 512; e += 256) {
        int v = 0;
        #pragma unroll
        for (int r = 0; r < NSREP; ++r) v += s_lds[r * SSTRIDE + e];
        atomicAdd(&g_s[h * 512 + e], v);
    }

    // ---- ticket protocol: release my atomics, take a ticket; last block
    // (ticket 1151) finalizes -- all 1151 others have already fenced.
    __threadfence();
    __syncthreads();
    if (t == 0) lastflag = (atomicAdd(done, 1) == 1151) ? 1 : 0;
    __syncthreads();
    if (!lastflag) return;
    __threadfence();   // acquire side

    // ---- final (one block): dc_new + output GEMV; agent-scope loads
    #pragma unroll
    for (int r = 0; r < 4; ++r) {
        const int i = r * 256 + t;
        const int v = __hip_atomic_load(&g_s[i], __ATOMIC_RELAXED,
                                        __HIP_MEMORY_SCOPE_AGENT);
        sf[i] = (float)v * INV_SEG_SCALE * (1.0f / NVOTES);
    }
    if (t < 80) {
        const int c = t >> 3, d = t & 7;
        const long long sv = __hip_atomic_load(&g_seg[c * 9 + d], __ATOMIC_RELAXED,
                                               __HIP_MEMORY_SCOPE_AGENT);
        const long long cv = __hip_atomic_load(&g_seg[c * 9 + 8], __ATOMIC_RELAXED,
                                               __HIP_MEMORY_SCOPE_AGENT);
        const float d0 = dc[t];
        const float nd = d0 + ((float)sv * INV_SEG_SCALE - (float)cv * d0) * (1.0f / DENOM);
        dcn[t] = nd;
        out[1280 + t] = nd;
    }
    __syncthreads();

    #pragma unroll
    for (int r = 0; r < 5; ++r) {
        const int idx = r * 256 + t;        // 0..1279
        const int b = idx / 10, c = idx - b * 10;
        float acc = 0.f;
        #pragma unroll
        for (int d = 0; d < 8; ++d) acc += sf[b * 8 + d] * dcn[c * 8 + d];
        out[idx] = acc;
    }
}

extern "C" void kernel_launch(void* const* d_in, const int* in_sizes, int n_in,
                              void* d_out, int out_size, void* d_ws, size_t ws_size,
                              hipStream_t stream) {
    const float* x  = (const float*)d_in[0];
    const float* w  = (const float*)d_in[1];
    const float* dc = (const float*)d_in[2];
    float* out = (float*)d_out;
    int*       done  = (int*)d_ws;
    long long* g_seg = (long long*)((char*)d_ws + 64);
    int*       g_s   = (int*)((char*)d_ws + 1024);

    // zero done + accumulators (workspace arrives poisoned); capture-safe
    hipMemsetAsync(d_ws, 0, 5120, stream);
    votes_kernel<<<1152, 256, 0, stream>>>(x, w, dc, g_seg, g_s, done, out);
}

// Round 5
// 107.185 us; speedup vs baseline: 1.5962x; 1.5962x over previous
//
#include <hip/hip_runtime.h>

// DigitCaps on MI355X, fp32 I/O. R16 = R13 votes (untouched, proven) +
// reduce rebuilt for parallelism (128 blocks x 9 rows, atomic combine,
// fused final via ticket).
// Session evidence:
//   R2: fp32 atomicAdd = CAS loop -> native int atomics only.
//   R3: seg sums winner-biased -> int64 finals.
//   R5/R7/R8: VGPR cap below natural demand -> scratch spill.
//   R9: register W-slice, replicated LDS atomics -> 99.4us baseline.
//   R10 neutral, R11 regression, R13 (dc->SGPR) neutral.
//   R14/R15: fusing final+atomic-flush INTO votes collapses codegen to
//     VGPR=64 regardless of launch_bounds (votes 120us). WRITE_SIZE there
//     = exactly the device-atomic bytes: device atomics bypass L2, pay
//     memory-side per-op. => votes body is OFF LIMITS; bulk atomic flush
//     from votes is out. This round: votes = R13 verbatim (minus done=0).
//   Old reduce analysis: 16 s-blocks x 144-load/thread chains over 2.36MB
//     HBM partials at ~700ns = ~12-15us latency-serial on 20 CUs. Fix:
//     128 blocks x 9 rows (18 loads/thread, one latency round), exact
//     int/int64 atomic combine into 5KB, ticket -> last block finalizes.
//
// Sizes: B=128, J=4608, INPUT_D=8, D=8, M=4 -> N=18432 votes, C=10.
// Output = concat(output[128,10], digit_caps_new[10,8]).
// Math: output[b,c] = <(1/N) sum_n u[b,n], dc_new[c]> -> only s[b,:] needed.
//
// ws layout (BYTES):
//   [0,4)              done ticket counter
//   [64,832)           g_seg long long[96]  (col c*9+d; d==8 -> count)
//   [1024,5120)        g_s   int[1024]      (col h*512 + local_b*8+d)
//   [8192,450560)      part_seg int [1152][96]
//   [450560,2809856)   part_s  int [1152][512]
//   memset span [0,5120).

#define J_POS 4608
#define SEGSTRIDE 97        // 97%32=1 -> replica r occupies bank r%32
#define NSEG 32
#define SSTRIDE 520
#define NSREP 8
#define NVOTES 18432.0f
#define DENOM  2359296.0f   // B*N
#define SEG_SCALE 32768.0f  // 2^15
#define INV_SEG_SCALE 3.0517578125e-5f

__global__ __launch_bounds__(256) void votes_kernel(
    const float* __restrict__ x,   // [B, J, 8]
    const float* __restrict__ w,   // [J, 8, 32]
    const float* __restrict__ dc,  // [10, 8]
    int* __restrict__ part_seg,
    int* __restrict__ part_s)
{
    __shared__ int seg_lds[NSEG * SEGSTRIDE];   // 12.4 KB
    __shared__ int s_lds[NSREP * SSTRIDE];      // 16.6 KB

    const int t  = threadIdx.x;
    const int jg = blockIdx.x >> 1;
    const int h  = blockIdx.x & 1;      // batch half
    const int j0 = jg * 8;

    for (int i = t; i < NSEG * SEGSTRIDE; i += 256) seg_lds[i] = 0;
    for (int i = t; i < NSREP * SSTRIDE; i += 256) s_lds[i] = 0;

    const int jj   = t >> 5;           // 0..7 : this thread's j
    const int m    = (t >> 3) & 3;     // 0..3 : this thread's vote column
    const int brow = t & 7;            // 0..7 : batch row within iter
    const int j = j0 + jj;

    // ---- W slice (8 i x 8 d for this (j,m)) -> 64 registers, loaded once
    float4 wra[8], wrb[8];
    {
        const float* wp = w + (size_t)j * 256 + m * 8;
        #pragma unroll
        for (int i = 0; i < 8; ++i) {
            wra[i] = *(const float4*)(wp + i * 32);
            wrb[i] = *(const float4*)(wp + i * 32 + 4);
        }
    }

    // ---- all of dc, forced wave-uniform (SGPR class via readfirstlane)
    float dcs[80];
    #pragma unroll
    for (int c = 0; c < 10; ++c) {
        const float4 a = *(const float4*)(dc + c * 8);
        const float4 b = *(const float4*)(dc + c * 8 + 4);
        dcs[c*8+0] = __uint_as_float(__builtin_amdgcn_readfirstlane(__float_as_uint(a.x)));
        dcs[c*8+1] = __uint_as_float(__builtin_amdgcn_readfirstlane(__float_as_uint(a.y)));
        dcs[c*8+2] = __uint_as_float(__builtin_amdgcn_readfirstlane(__float_as_uint(a.z)));
        dcs[c*8+3] = __uint_as_float(__builtin_amdgcn_readfirstlane(__float_as_uint(a.w)));
        dcs[c*8+4] = __uint_as_float(__builtin_amdgcn_readfirstlane(__float_as_uint(b.x)));
        dcs[c*8+5] = __uint_as_float(__builtin_amdgcn_readfirstlane(__float_as_uint(b.y)));
        dcs[c*8+6] = __uint_as_float(__builtin_amdgcn_readfirstlane(__float_as_uint(b.z)));
        dcs[c*8+7] = __uint_as_float(__builtin_amdgcn_readfirstlane(__float_as_uint(b.w)));
    }

    int* const segp = &seg_lds[((t >> 1) & (NSEG - 1)) * SEGSTRIDE];
    // lanes sharing one b in a wave = {jj&1, m} -> 8 distinct replicas: 1-way
    int* const sp = &s_lds[((t >> 3) & (NSREP - 1)) * SSTRIDE];

    __syncthreads();

    // ---- software-pipelined x loads (1-ahead) to hide HBM latency
    const float* xp0 = x + ((size_t)(h * 64 + brow) * J_POS + j) * 8;
    float4 nx0 = *(const float4*)xp0;
    float4 nx1 = *(const float4*)(xp0 + 4);

    #pragma unroll 1
    for (int it = 0; it < 8; ++it) {
        const int bl = it * 8 + brow;       // local b 0..63
        const float4 x0 = nx0, x1 = nx1;
        if (it < 7) {
            const float* xp = x + ((size_t)(h * 64 + bl + 8) * J_POS + j) * 8;
            nx0 = *(const float4*)xp;
            nx1 = *(const float4*)(xp + 4);
        }
        const float xf[8] = {x0.x,x0.y,x0.z,x0.w,x1.x,x1.y,x1.z,x1.w};

        // ---- one vote: u[8], all operands in registers
        float u[8] = {0,0,0,0,0,0,0,0};
        #pragma unroll
        for (int i = 0; i < 8; ++i) {
            const float xi = xf[i];
            u[0] += xi * wra[i].x; u[1] += xi * wra[i].y;
            u[2] += xi * wra[i].z; u[3] += xi * wra[i].w;
            u[4] += xi * wrb[i].x; u[5] += xi * wrb[i].y;
            u[6] += xi * wrb[i].z; u[7] += xi * wrb[i].w;
        }

        // ---- argmax over 10 caps (strict > = first max, jnp)
        float best = -3.402823466e38f;
        int bc = 0;
        #pragma unroll
        for (int c = 0; c < 10; ++c) {
            const float sim = u[0]*dcs[c*8+0] + u[1]*dcs[c*8+1]
                            + u[2]*dcs[c*8+2] + u[3]*dcs[c*8+3]
                            + u[4]*dcs[c*8+4] + u[5]*dcs[c*8+5]
                            + u[6]*dcs[c*8+6] + u[7]*dcs[c*8+7];
            if (sim > best) { best = sim; bc = c; }
        }

        // ---- fixed-point LDS atomics, fire-and-forget
        const int o = bc * 9;
        const int sb = bl * 8;
        #pragma unroll
        for (int d = 0; d < 8; ++d) {
            const int q = __float2int_rn(u[d] * SEG_SCALE);
            atomicAdd(&segp[o + d], q);
            atomicAdd(&sp[sb + d], q);
        }
        atomicAdd(&segp[o + 8], 1);
    }

    __syncthreads();

    // ---- flush partials: plain coalesced stores, zero global atomics
    if (t < 90) {
        int v = 0;
        #pragma unroll
        for (int r = 0; r < NSEG; ++r) v += seg_lds[r * SEGSTRIDE + t];
        part_seg[blockIdx.x * 96 + t] = v;
    }
    #pragma unroll
    for (int e = t; e < 512; e += 256) {
        int v = 0;
        #pragma unroll
        for (int r = 0; r < NSREP; ++r) v += s_lds[r * SSTRIDE + e];
        part_s[(size_t)blockIdx.x * 512 + e] = v;
    }
}

// 128 blocks x 9 rows each; exact integer atomic combine; last ticket
// holder (127) runs the final dc_new + output GEMV.
__global__ __launch_bounds__(256) void reduce_final_kernel(
    const int* __restrict__ part_seg,
    const int* __restrict__ part_s,
    long long* __restrict__ g_seg,  // [96]
    int* __restrict__ g_s,          // [1024] col h*512 + e
    int* __restrict__ done,
    const float* __restrict__ dc,
    float* __restrict__ out)        // [0,1280): output  [1280,1360): dc_new
{
    __shared__ float sf[1024];
    __shared__ float dcn[80];
    __shared__ int lastflag;

    const int t = threadIdx.x;
    const int r0 = blockIdx.x * 9;

    // ---- s rows: 2 cols/thread, 9 rows, parity h selects global half.
    // Predicated accumulate (no dynamic indexing -> no scratch, rule #20).
    int accA0 = 0, accB0 = 0, accA1 = 0, accB1 = 0;
    #pragma unroll
    for (int i = 0; i < 9; ++i) {
        const int r = r0 + i;
        const int hh = r & 1;
        const int v0 = part_s[(size_t)r * 512 + t];
        const int v1 = part_s[(size_t)r * 512 + t + 256];
        accA0 += hh ? 0 : v0;  accB0 += hh ? v0 : 0;
        accA1 += hh ? 0 : v1;  accB1 += hh ? v1 : 0;
    }
    atomicAdd(&g_s[t],       accA0);
    atomicAdd(&g_s[512 + t], accB0);
    atomicAdd(&g_s[t + 256],       accA1);
    atomicAdd(&g_s[512 + t + 256], accB1);

    // ---- seg rows: threads 0..95 own one column each (9-row partial fits
    // int32: <= 9*128 votes * max|q| ~ 3.2e8 < 2^31)
    if (t < 96) {
        int acc = 0;
        #pragma unroll
        for (int i = 0; i < 9; ++i)
            acc += part_seg[(size_t)(r0 + i) * 96 + t];
        atomicAdd((unsigned long long*)&g_seg[t],
                  (unsigned long long)(long long)acc);
    }

    // ---- ticket protocol (proven in R14/R15): release, count, last runs.
    __threadfence();
    __syncthreads();
    if (t == 0) lastflag = (atomicAdd(done, 1) == 127) ? 1 : 0;
    __syncthreads();
    if (!lastflag) return;
    __threadfence();   // acquire side

    // ---- final (one block): dc_new + output GEMV; agent-scope loads.
    // Same float op order as R13: (float)intsum * INV then * 1/NVOTES.
    #pragma unroll
    for (int r = 0; r < 4; ++r) {
        const int i = r * 256 + t;
        const int v = __hip_atomic_load(&g_s[i], __ATOMIC_RELAXED,
                                        __HIP_MEMORY_SCOPE_AGENT);
        sf[i] = ((float)v * INV_SEG_SCALE) * (1.0f / NVOTES);
    }
    if (t < 80) {
        const int c = t >> 3, d = t & 7;
        const long long sv = __hip_atomic_load(&g_seg[c * 9 + d], __ATOMIC_RELAXED,
                                               __HIP_MEMORY_SCOPE_AGENT);
        const long long cv = __hip_atomic_load(&g_seg[c * 9 + 8], __ATOMIC_RELAXED,
                                               __HIP_MEMORY_SCOPE_AGENT);
        const float d0 = dc[t];
        const float nd = d0 + ((float)sv * INV_SEG_SCALE - (float)cv * d0) * (1.0f / DENOM);
        dcn[t] = nd;
        out[1280 + t] = nd;
    }
    __syncthreads();

    #pragma unroll
    for (int r = 0; r < 5; ++r) {
        const int idx = r * 256 + t;        // 0..1279
        const int b = idx / 10, c = idx - b * 10;
        float acc = 0.f;
        #pragma unroll
        for (int d = 0; d < 8; ++d) acc += sf[b * 8 + d] * dcn[c * 8 + d];
        out[idx] = acc;
    }
}

extern "C" void kernel_launch(void* const* d_in, const int* in_sizes, int n_in,
                              void* d_out, int out_size, void* d_ws, size_t ws_size,
                              hipStream_t stream) {
    const float* x  = (const float*)d_in[0];
    const float* w  = (const float*)d_in[1];
    const float* dc = (const float*)d_in[2];
    float* out = (float*)d_out;
    int*       done     = (int*)d_ws;
    long long* g_seg    = (long long*)((char*)d_ws + 64);
    int*       g_s      = (int*)((char*)d_ws + 1024);
    int*       part_seg = (int*)((char*)d_ws + 8192);
    int*       part_s   = (int*)((char*)d_ws + 450560);

    // zero done + tiny accumulators (workspace arrives poisoned)
    hipMemsetAsync(d_ws, 0, 5120, stream);
    votes_kernel<<<1152, 256, 0, stream>>>(x, w, dc, part_seg, part_s);
    reduce_final_kernel<<<128, 256, 0, stream>>>(part_seg, part_s, g_seg, g_s,
                                                 done, dc, out);
}

// Round 6
// 101.407 us; speedup vs baseline: 1.6871x; 1.0570x over previous
//
#include <hip/hip_runtime.h>

// DigitCaps on MI355X, fp32 I/O. R17 = R13 votes (verbatim, proven 99-100us
// twice) + reduce rebuilt as a latency-balanced TWO-STAGE kernel, no global
// atomics (R16 lesson: atomic combine to few addresses serializes memory-
// side; regressed +7us).
// Session evidence:
//   R2: fp32 atomicAdd = CAS loop -> native int atomics only.
//   R3: seg sums winner-biased -> int64 on multi-block sums.
//   R5/R7/R8: VGPR cap below natural demand -> scratch spill.
//   R9: register W-slice, replicated LDS atomics -> 99.4us baseline.
//   R10 neutral, R11 regression, R13 (dc->SGPR) neutral (99.2-100.2 band).
//   R14/R15: final fused INTO votes collapses codegen to VGPR=64 -> spill.
//     votes body is OFF LIMITS.
//   R16: 128-block reduce w/ 131K device atomics onto 1.1K addrs -> +7us.
//     Cross-block combine must be plain stores + ticket + agent loads.
//   R13 reduce analysis: 16 s-blocks x 144-load chains @ ~8-16 ILP over
//     2.36MB HBM partials ~= 12-15us. This round: stage A 32 blocks x 36
//     rows (36 int2 loads, fully unrollable -> 1-2 latency rounds) ->
//     part2[32][1024+96] agent stores (156KB); ticket; last block stage B:
//     32-row chains (L3-resident) + unchanged final. Balanced optimum P=32.
//
// Sizes: B=128, J=4608, INPUT_D=8, D=8, M=4 -> N=18432 votes, C=10.
// Output = concat(output[128,10], digit_caps_new[10,8]).
// Math: output[b,c] = <(1/N) sum_n u[b,n], dc_new[c]> -> only s[b,:] needed.
//
// ws layout (BYTES):
//   [0,4)               done ticket counter (zeroed by votes block 0)
//   [64,24640)          part2_seg ll[32][96]  (col c*9+d; d==8 -> count)
//   [24640,155712)      part2_s  int[32][1024] (col h*512 + local_b*8+d)
//   [155712,598080)     part_seg int[1152][96]
//   [598080,2957376)    part_s   int[1152][512]

#define J_POS 4608
#define SEGSTRIDE 97        // 97%32=1 -> replica r occupies bank r%32
#define NSEG 32
#define SSTRIDE 520
#define NSREP 8
#define NVOTES 18432.0f
#define DENOM  2359296.0f   // B*N
#define SEG_SCALE 32768.0f  // 2^15
#define INV_SEG_SCALE 3.0517578125e-5f
#define P2 32
#define ROWS_PER 36         // 32*36 = 1152

__global__ __launch_bounds__(256) void votes_kernel(
    const float* __restrict__ x,   // [B, J, 8]
    const float* __restrict__ w,   // [J, 8, 32]
    const float* __restrict__ dc,  // [10, 8]
    int* __restrict__ part_seg,
    int* __restrict__ part_s,
    int* __restrict__ done)
{
    __shared__ int seg_lds[NSEG * SEGSTRIDE];   // 12.4 KB
    __shared__ int s_lds[NSREP * SSTRIDE];      // 16.6 KB

    const int t  = threadIdx.x;
    const int jg = blockIdx.x >> 1;
    const int h  = blockIdx.x & 1;      // batch half
    const int j0 = jg * 8;

    if (blockIdx.x == 0 && t == 0) *done = 0;   // reduce launches after us (stream order)

    for (int i = t; i < NSEG * SEGSTRIDE; i += 256) seg_lds[i] = 0;
    for (int i = t; i < NSREP * SSTRIDE; i += 256) s_lds[i] = 0;

    const int jj   = t >> 5;           // 0..7 : this thread's j
    const int m    = (t >> 3) & 3;     // 0..3 : this thread's vote column
    const int brow = t & 7;            // 0..7 : batch row within iter
    const int j = j0 + jj;

    // ---- W slice (8 i x 8 d for this (j,m)) -> 64 registers, loaded once
    float4 wra[8], wrb[8];
    {
        const float* wp = w + (size_t)j * 256 + m * 8;
        #pragma unroll
        for (int i = 0; i < 8; ++i) {
            wra[i] = *(const float4*)(wp + i * 32);
            wrb[i] = *(const float4*)(wp + i * 32 + 4);
        }
    }

    // ---- all of dc, forced wave-uniform (SGPR class via readfirstlane)
    float dcs[80];
    #pragma unroll
    for (int c = 0; c < 10; ++c) {
        const float4 a = *(const float4*)(dc + c * 8);
        const float4 b = *(const float4*)(dc + c * 8 + 4);
        dcs[c*8+0] = __uint_as_float(__builtin_amdgcn_readfirstlane(__float_as_uint(a.x)));
        dcs[c*8+1] = __uint_as_float(__builtin_amdgcn_readfirstlane(__float_as_uint(a.y)));
        dcs[c*8+2] = __uint_as_float(__builtin_amdgcn_readfirstlane(__float_as_uint(a.z)));
        dcs[c*8+3] = __uint_as_float(__builtin_amdgcn_readfirstlane(__float_as_uint(a.w)));
        dcs[c*8+4] = __uint_as_float(__builtin_amdgcn_readfirstlane(__float_as_uint(b.x)));
        dcs[c*8+5] = __uint_as_float(__builtin_amdgcn_readfirstlane(__float_as_uint(b.y)));
        dcs[c*8+6] = __uint_as_float(__builtin_amdgcn_readfirstlane(__float_as_uint(b.z)));
        dcs[c*8+7] = __uint_as_float(__builtin_amdgcn_readfirstlane(__float_as_uint(b.w)));
    }

    int* const segp = &seg_lds[((t >> 1) & (NSEG - 1)) * SEGSTRIDE];
    // lanes sharing one b in a wave = {jj&1, m} -> 8 distinct replicas: 1-way
    int* const sp = &s_lds[((t >> 3) & (NSREP - 1)) * SSTRIDE];

    __syncthreads();

    // ---- software-pipelined x loads (1-ahead) to hide HBM latency
    const float* xp0 = x + ((size_t)(h * 64 + brow) * J_POS + j) * 8;
    float4 nx0 = *(const float4*)xp0;
    float4 nx1 = *(const float4*)(xp0 + 4);

    #pragma unroll 1
    for (int it = 0; it < 8; ++it) {
        const int bl = it * 8 + brow;       // local b 0..63
        const float4 x0 = nx0, x1 = nx1;
        if (it < 7) {
            const float* xp = x + ((size_t)(h * 64 + bl + 8) * J_POS + j) * 8;
            nx0 = *(const float4*)xp;
            nx1 = *(const float4*)(xp + 4);
        }
        const float xf[8] = {x0.x,x0.y,x0.z,x0.w,x1.x,x1.y,x1.z,x1.w};

        // ---- one vote: u[8], all operands in registers
        float u[8] = {0,0,0,0,0,0,0,0};
        #pragma unroll
        for (int i = 0; i < 8; ++i) {
            const float xi = xf[i];
            u[0] += xi * wra[i].x; u[1] += xi * wra[i].y;
            u[2] += xi * wra[i].z; u[3] += xi * wra[i].w;
            u[4] += xi * wrb[i].x; u[5] += xi * wrb[i].y;
            u[6] += xi * wrb[i].z; u[7] += xi * wrb[i].w;
        }

        // ---- argmax over 10 caps (strict > = first max, jnp)
        float best = -3.402823466e38f;
        int bc = 0;
        #pragma unroll
        for (int c = 0; c < 10; ++c) {
            const float sim = u[0]*dcs[c*8+0] + u[1]*dcs[c*8+1]
                            + u[2]*dcs[c*8+2] + u[3]*dcs[c*8+3]
                            + u[4]*dcs[c*8+4] + u[5]*dcs[c*8+5]
                            + u[6]*dcs[c*8+6] + u[7]*dcs[c*8+7];
            if (sim > best) { best = sim; bc = c; }
        }

        // ---- fixed-point LDS atomics, fire-and-forget
        const int o = bc * 9;
        const int sb = bl * 8;
        #pragma unroll
        for (int d = 0; d < 8; ++d) {
            const int q = __float2int_rn(u[d] * SEG_SCALE);
            atomicAdd(&segp[o + d], q);
            atomicAdd(&sp[sb + d], q);
        }
        atomicAdd(&segp[o + 8], 1);
    }

    __syncthreads();

    // ---- flush partials: plain coalesced stores, zero global atomics
    if (t < 90) {
        int v = 0;
        #pragma unroll
        for (int r = 0; r < NSEG; ++r) v += seg_lds[r * SEGSTRIDE + t];
        part_seg[blockIdx.x * 96 + t] = v;
    }
    #pragma unroll
    for (int e = t; e < 512; e += 256) {
        int v = 0;
        #pragma unroll
        for (int r = 0; r < NSREP; ++r) v += s_lds[r * SSTRIDE + e];
        part_s[(size_t)blockIdx.x * 512 + e] = v;
    }
}

// 32 blocks. Stage A: each reduces 36 rows -> part2 (agent stores).
// Ticket; last block runs stage B (32-row chains, L3-resident) + final.
__global__ __launch_bounds__(256) void reduce_final_kernel(
    const int* __restrict__ part_seg,
    const int* __restrict__ part_s,
    int* __restrict__ part2_s,         // [32][1024]
    long long* __restrict__ part2_seg, // [32][96]
    int* __restrict__ done,
    const float* __restrict__ dc,
    float* __restrict__ out)           // [0,1280): output  [1280,1360): dc_new
{
    __shared__ float sf[1024];
    __shared__ float dcn[80];
    __shared__ int lastflag;

    const int t = threadIdx.x;
    const int p = blockIdx.x;
    const int r0 = p * ROWS_PER;       // even, so row parity == (i&1)

    // ---- stage A, s: cols (2t, 2t+1) via int2, 36 rows, parity-split.
    // Fully unrolled: all 36 loads issued before use -> ~1-2 HBM rounds.
    int aE0 = 0, aE1 = 0, aO0 = 0, aO1 = 0;
    #pragma unroll
    for (int i = 0; i < ROWS_PER; ++i) {
        const int2 v = *(const int2*)(part_s + (size_t)(r0 + i) * 512 + 2 * t);
        if (i & 1) { aO0 += v.x; aO1 += v.y; }
        else       { aE0 += v.x; aE1 += v.y; }
    }
    __hip_atomic_store(&part2_s[p * 1024 + 2 * t],       aE0, __ATOMIC_RELAXED, __HIP_MEMORY_SCOPE_AGENT);
    __hip_atomic_store(&part2_s[p * 1024 + 2 * t + 1],   aE1, __ATOMIC_RELAXED, __HIP_MEMORY_SCOPE_AGENT);
    __hip_atomic_store(&part2_s[p * 1024 + 512 + 2 * t],     aO0, __ATOMIC_RELAXED, __HIP_MEMORY_SCOPE_AGENT);
    __hip_atomic_store(&part2_s[p * 1024 + 512 + 2 * t + 1], aO1, __ATOMIC_RELAXED, __HIP_MEMORY_SCOPE_AGENT);

    // ---- stage A, seg: col t (t<96), int64 acc (36-row winner-biased sums
    // can exceed int32 -- R3 lesson).
    if (t < 96) {
        long long acc = 0;
        #pragma unroll
        for (int i = 0; i < ROWS_PER; ++i)
            acc += part_seg[(size_t)(r0 + i) * 96 + t];
        __hip_atomic_store(&part2_seg[p * 96 + t], acc,
                           __ATOMIC_RELAXED, __HIP_MEMORY_SCOPE_AGENT);
    }

    // ---- ticket protocol (R13-proven): release, count, last finalizes.
    __threadfence();
    __syncthreads();
    if (t == 0) lastflag = (atomicAdd(done, 1) == P2 - 1) ? 1 : 0;
    __syncthreads();
    if (!lastflag) return;
    __threadfence();   // acquire side

    // ---- stage B, s totals: 4 cols/thread x 32 rows; int32 exact (proven
    // R14: full s totals fit int32). Same float op order as R13:
    // ((float)total * INV_SEG_SCALE) * (1/NVOTES) -> bit-identical.
    #pragma unroll
    for (int g = 0; g < 2; ++g) {
        const int c0 = g * 512 + 2 * t;
        int t0 = 0, t1 = 0;
        #pragma unroll
        for (int q = 0; q < P2; ++q) {
            t0 += __hip_atomic_load(&part2_s[q * 1024 + c0],     __ATOMIC_RELAXED, __HIP_MEMORY_SCOPE_AGENT);
            t1 += __hip_atomic_load(&part2_s[q * 1024 + c0 + 1], __ATOMIC_RELAXED, __HIP_MEMORY_SCOPE_AGENT);
        }
        sf[c0]     = ((float)t0 * INV_SEG_SCALE) * (1.0f / NVOTES);
        sf[c0 + 1] = ((float)t1 * INV_SEG_SCALE) * (1.0f / NVOTES);
    }

    // ---- stage B, seg: (c,d) per thread, 32-row ll chains.
    if (t < 80) {
        const int c = t >> 3, d = t & 7;
        long long sv = 0, cv = 0;
        #pragma unroll
        for (int q = 0; q < P2; ++q) {
            sv += __hip_atomic_load(&part2_seg[q * 96 + c * 9 + d], __ATOMIC_RELAXED, __HIP_MEMORY_SCOPE_AGENT);
            cv += __hip_atomic_load(&part2_seg[q * 96 + c * 9 + 8], __ATOMIC_RELAXED, __HIP_MEMORY_SCOPE_AGENT);
        }
        const float d0 = dc[t];
        const float nd = d0 + ((float)sv * INV_SEG_SCALE - (float)cv * d0) * (1.0f / DENOM);
        dcn[t] = nd;
        out[1280 + t] = nd;
    }
    __syncthreads();

    #pragma unroll
    for (int r = 0; r < 5; ++r) {
        const int idx = r * 256 + t;        // 0..1279
        const int b = idx / 10, c = idx - b * 10;
        float acc = 0.f;
        #pragma unroll
        for (int d = 0; d < 8; ++d) acc += sf[b * 8 + d] * dcn[c * 8 + d];
        out[idx] = acc;
    }
}

extern "C" void kernel_launch(void* const* d_in, const int* in_sizes, int n_in,
                              void* d_out, int out_size, void* d_ws, size_t ws_size,
                              hipStream_t stream) {
    const float* x  = (const float*)d_in[0];
    const float* w  = (const float*)d_in[1];
    const float* dc = (const float*)d_in[2];
    float* out = (float*)d_out;
    int*       done      = (int*)d_ws;
    long long* part2_seg = (long long*)((char*)d_ws + 64);
    int*       part2_s   = (int*)((char*)d_ws + 24640);
    int*       part_seg  = (int*)((char*)d_ws + 155712);
    int*       part_s    = (int*)((char*)d_ws + 598080);

    votes_kernel<<<1152, 256, 0, stream>>>(x, w, dc, part_seg, part_s, done);
    reduce_final_kernel<<<P2, 256, 0, stream>>>(part_seg, part_s, part2_s,
                                                part2_seg, done, dc, out);
}